// Round 1
// baseline (1181.150 us; speedup 1.0000x reference)
//
#include <hip/hip_runtime.h>
#include <hip/hip_bf16.h>

#define VOCAB 32000
#define EMB 64
#define BATCH 4
#define SEQ 2048
#define CHUNK 128
#define NCHUNK (SEQ / CHUNK)   // 16
#define M_TOTAL (BATCH * SEQ)  // 8192

// GEMM tiling: block = 4 waves, each wave = 32 rows (2 m-tiles) x SLAB cols
#define SLAB 320               // cols per block
#define GX (VOCAB / SLAB)      // 100 N-blocks
#define GY (M_TOTAL / 128)     // 64  M-blocks (128 rows per block)
#define NBLK (GX * GY)         // 6400, divisible by 8 XCDs -> 800 each

typedef __bf16 bf16x8 __attribute__((ext_vector_type(8)));
typedef float f32x4 __attribute__((ext_vector_type(4)));

// ---- Pass 1: per-chunk partial sums of gathered embeddings ----
// grid (BATCH, NCHUNK), block 64 (thread = emb dim)
__global__ void k_partial(const float* __restrict__ emb, const int* __restrict__ x,
                          float* __restrict__ partial) {
    int b = blockIdx.x, c = blockIdx.y, e = threadIdx.x;
    const int base = b * SEQ + c * CHUNK;
    float s = 0.f;
#pragma unroll 4
    for (int p = 0; p < CHUNK; ++p) {
        int row = x[base + p];
        s += emb[row * EMB + e];
    }
    partial[(b * NCHUNK + c) * EMB + e] = s;
}

// ---- Pass 2: running prefix mean within chunk, write bf16 A ----
// grid (BATCH, NCHUNK), block 64
__global__ void k_prefix(const float* __restrict__ emb, const int* __restrict__ x,
                         const float* __restrict__ partial,
                         __hip_bfloat16* __restrict__ A) {
    int b = blockIdx.x, c = blockIdx.y, e = threadIdx.x;
    float s = 0.f;
    for (int j = 0; j < c; ++j) s += partial[(b * NCHUNK + j) * EMB + e];
    const int base = b * SEQ + c * CHUNK;
#pragma unroll 4
    for (int p = 0; p < CHUNK; ++p) {
        int row = x[base + p];
        s += emb[row * EMB + e];
        int pos = c * CHUNK + p;               // position within sequence
        float mean = s / (float)(pos + 1);
        A[(base + p) * EMB + e] = __float2bfloat16(mean);
    }
}

// ---- W fp32 -> bf16 (keeps N x K row-major = B^T layout) ----
__global__ void k_conv(const float* __restrict__ W, __hip_bfloat16* __restrict__ Wb, int n) {
    int i = blockIdx.x * blockDim.x + threadIdx.x;
    int stride = gridDim.x * blockDim.x;
    for (; i < n; i += stride) Wb[i] = __float2bfloat16(W[i]);
}

// ---- GEMM: C(8192 x 32000) = A(8192x64,bf16) * Wb^T + bias, fp32 out ----
// Swapped-operand MFMA: D = mfma(W_frag, A_frag) so each lane holds 4
// CONSECUTIVE output columns -> one dwordx4 non-temporal store per tile.
// Layouts (16x16x32 bf16, verified):
//   A-slot (W):  va[j] = W[n = lane&15][k = (lane>>4)*8 + j]   (Wb is N x K row-major)
//   B-slot (A):  vb[j] = A[m = lane&15][k = (lane>>4)*8 + j]   (A^T as K x M)
//   D:           lane(q,l), reg r -> C[m = l][n = ntile + q*4 + r]
__global__ __launch_bounds__(256) void k_gemm(const __hip_bfloat16* __restrict__ A,
                                              const __hip_bfloat16* __restrict__ Wb,
                                              const float* __restrict__ bias,
                                              float* __restrict__ C) {
    // bijective XCD swizzle: XCD k owns swz in [k*800, (k+1)*800)
    // -> each XCD gets a contiguous 1024-row band of C (contiguous write streams)
    //    and re-reads all of Wb (4 MB) from its own L2.
    const int lid = blockIdx.x + gridDim.x * blockIdx.y;
    const int swz = (lid & 7) * (NBLK / 8) + (lid >> 3);
    const int xn = swz % GX;
    const int ym = swz / GX;

    const int wave = threadIdx.x >> 6;
    const int lane = threadIdx.x & 63;
    const int quad = lane >> 4;
    const int lo16 = lane & 15;

    const int m_base = ym * 128 + wave * 32;   // wave owns 2 m-tiles
    const int n_slab = xn * SLAB;

    const int m0 = m_base + lo16;
    const int m1 = m0 + 16;
    // A fragments for both m-tiles, full K=64, live for the whole N loop
    bf16x8 a0 = *reinterpret_cast<const bf16x8*>(A + (size_t)m0 * EMB + quad * 8);
    bf16x8 a1 = *reinterpret_cast<const bf16x8*>(A + (size_t)m0 * EMB + 32 + quad * 8);
    bf16x8 a2 = *reinterpret_cast<const bf16x8*>(A + (size_t)m1 * EMB + quad * 8);
    bf16x8 a3 = *reinterpret_cast<const bf16x8*>(A + (size_t)m1 * EMB + 32 + quad * 8);

    for (int nt = 0; nt < SLAB; nt += 16) {
        const int nw = n_slab + nt + lo16;          // W row for fragment load
        bf16x8 w0 = *reinterpret_cast<const bf16x8*>(Wb + (size_t)nw * EMB + quad * 8);
        bf16x8 w1 = *reinterpret_cast<const bf16x8*>(Wb + (size_t)nw * EMB + 32 + quad * 8);

        const int nc = n_slab + nt + quad * 4;      // this lane's 4 output cols
        f32x4 acc0 = *reinterpret_cast<const f32x4*>(bias + nc);  // broadcast per quad
        f32x4 acc1 = acc0;

        acc0 = __builtin_amdgcn_mfma_f32_16x16x32_bf16(w0, a0, acc0, 0, 0, 0);
        acc0 = __builtin_amdgcn_mfma_f32_16x16x32_bf16(w1, a1, acc0, 0, 0, 0);
        acc1 = __builtin_amdgcn_mfma_f32_16x16x32_bf16(w0, a2, acc1, 0, 0, 0);
        acc1 = __builtin_amdgcn_mfma_f32_16x16x32_bf16(w1, a3, acc1, 0, 0, 0);

        // one 16B non-temporal store per m-tile (evict-first: don't thrash Wb in L2)
        __builtin_nontemporal_store(acc0, reinterpret_cast<f32x4*>(C + (size_t)m0 * VOCAB + nc));
        __builtin_nontemporal_store(acc1, reinterpret_cast<f32x4*>(C + (size_t)m1 * VOCAB + nc));
    }
}

extern "C" void kernel_launch(void* const* d_in, const int* in_sizes, int n_in,
                              void* d_out, int out_size, void* d_ws, size_t ws_size,
                              hipStream_t stream) {
    const float* emb  = (const float*)d_in[0];  // (32000, 64)
    const float* W    = (const float*)d_in[1];  // (32000, 64)
    const float* bias = (const float*)d_in[2];  // (32000,)
    const int*   x    = (const int*)d_in[3];    // (4, 2048)
    float* C = (float*)d_out;                   // (4, 2048, 32000)

    // workspace layout
    char* ws = (char*)d_ws;
    __hip_bfloat16* A  = (__hip_bfloat16*)ws;                       // 8192*64*2 = 1,048,576 B
    __hip_bfloat16* Wb = (__hip_bfloat16*)(ws + 1048576);           // 32000*64*2 = 4,096,000 B
    float* partial     = (float*)(ws + 1048576 + 4096000);          // 4*16*64*4 = 16,384 B

    k_partial<<<dim3(BATCH, NCHUNK), 64, 0, stream>>>(emb, x, partial);
    k_conv<<<2048, 256, 0, stream>>>(W, Wb, VOCAB * EMB);
    k_prefix<<<dim3(BATCH, NCHUNK), 64, 0, stream>>>(emb, x, partial, A);
    k_gemm<<<dim3(GX, GY), 256, 0, stream>>>(A, Wb, bias, C);
}